// Round 13
// baseline (633.900 us; speedup 1.0000x reference)
//
#include <hip/hip_runtime.h>
#include <hip/hip_bf16.h>

// Problem: out = lecac_linear(relu(lecac_linear(x, W1, b1)), W2, b2)
//   x: [262144, 256] f32, W1: [512,256], b1: [512], W2: [256,512], b2: [256]
// R13: R12 (unfused 2-pass, BM=32, LDS-staged activations, bf16 weight table
// in L2) + EXPLICIT DEPTH-2 WEIGHT PREFETCH (R3's rotating-buffer pattern).
// R12 deleted R10's 109us unpack-VALU stream but exposed L2 latency instead
// (VGPR=40: compiler kept loads just-in-time; 250cyc round-trip per kk vs
// 40cyc MFMA). Manual depth-2 pipeline: kk=0,1 frags issued before the
// activation stage (latency under stage+barrier), each kk refills buffer
// (kk&1) for kk+2 with static indices -> stays in registers (~+16 VGPR).

typedef __attribute__((ext_vector_type(8))) short bf16x8;
typedef __attribute__((ext_vector_type(4))) float f32x4;
typedef __attribute__((ext_vector_type(4))) unsigned short us4;

#define D_IN 256
#define D_HID 512
#define D_OUT 256
#define BM 32

__device__ __forceinline__ unsigned short f2bf(float f) {
  union { __hip_bfloat16 h; unsigned short u; } c;
  c.h = __float2bfloat16(f);
  return c.u;
}

__device__ __forceinline__ bf16x8 cvt8(float4 lo, float4 hi) {
  bf16x8 v;
  v[0] = (short)f2bf(lo.x); v[1] = (short)f2bf(lo.y);
  v[2] = (short)f2bf(lo.z); v[3] = (short)f2bf(lo.w);
  v[4] = (short)f2bf(hi.x); v[5] = (short)f2bf(hi.y);
  v[6] = (short)f2bf(hi.z); v[7] = (short)f2bf(hi.w);
  return v;
}

// DMA 16B per lane: global (per-lane addr) -> LDS (wave-uniform base + lane*16)
__device__ __forceinline__ void gload_lds16(const unsigned short* g, unsigned short* l) {
  __builtin_amdgcn_global_load_lds(
      (const __attribute__((address_space(1))) void*)(const void*)g,
      (__attribute__((address_space(3))) void*)(void*)l, 16, 0, 0);
}

// ---- prep 1: deterministic f64 partial abs-sums (8 chunks per tensor) ------
__global__ void partial_abs_kernel(const float* __restrict__ W1,
                                   const float* __restrict__ W2,
                                   double* __restrict__ part) {
  const int b = blockIdx.x;                 // 0..15
  const float* W = (b < 8) ? W1 : W2;
  const float* p = W + (b & 7) * 16384;     // 131072 / 8
  double s = 0.0;
  for (int i = threadIdx.x; i < 16384; i += 1024) s += (double)fabsf(p[i]);
  __shared__ double red[1024];
  red[threadIdx.x] = s;
  __syncthreads();
  for (int st = 512; st > 0; st >>= 1) {
    if (threadIdx.x < st) red[threadIdx.x] += red[threadIdx.x + st];
    __syncthreads();
  }
  if (threadIdx.x == 0) part[b] = red[0];
}

// ---- prep 2: quantize codes to bf16 tables (exact ints in bf16) ------------
__global__ void quant_kernel(const float* __restrict__ W1,
                             const float* __restrict__ W2,
                             const double* __restrict__ part,
                             unsigned short* __restrict__ w1c,
                             unsigned short* __restrict__ w2c,
                             float* __restrict__ fscales) {
  int idx = blockIdx.x * blockDim.x + threadIdx.x;  // 65536 float4 chunks
  bool is2 = idx >= 32768;
  const float4* src = is2 ? (const float4*)W2 : (const float4*)W1;
  us4* dst = is2 ? (us4*)w2c : (us4*)w1c;
  int i = is2 ? idx - 32768 : idx;
  const double* pp = part + (is2 ? 8 : 0);
  double sum = ((pp[0] + pp[1]) + (pp[2] + pp[3])) + ((pp[4] + pp[5]) + (pp[6] + pp[7]));
  double s = 1.47 * (sum / 131072.0) + 1e-8;
  if (idx == 0) {
    const double* q = part;
    double s0 = 1.47 * ((((q[0]+q[1])+(q[2]+q[3]))+((q[4]+q[5])+(q[6]+q[7]))) / 131072.0) + 1e-8;
    double s1 = 1.47 * ((((q[8]+q[9])+(q[10]+q[11]))+((q[12]+q[13])+(q[14]+q[15]))) / 131072.0) + 1e-8;
    fscales[0] = (float)s0;
    fscales[1] = (float)s1;
  }
  float4 v = src[i];
  us4 o;
  // round-half-even in f64 to match the float64 numpy ref at boundaries
  o.x = f2bf((float)fmin(fmax(rint((double)v.x / s), -2.0), 1.0));
  o.y = f2bf((float)fmin(fmax(rint((double)v.y / s), -2.0), 1.0));
  o.z = f2bf((float)fmin(fmax(rint((double)v.z / s), -2.0), 1.0));
  o.w = f2bf((float)fmin(fmax(rint((double)v.w / s), -2.0), 1.0));
  dst[i] = o;
}

// ---------------- K1: h = relu(s1 * (W1q @ x^T) + b1), h bf16 ---------------
// 8192 blocks x 512 threads (8 waves). Block = 32 batch rows. Wave wv owns
// hidden rows [64wv, 64wv+64). x tile reg-staged to LDS as bf16 (16 KB),
// swizzled slot^((row&7)<<2). Weight A-frags: L2-resident bf16 table,
// depth-2 rotating-buffer prefetch.
__launch_bounds__(512)
__global__ void k1_gemm(const float* __restrict__ x,
                        const float* __restrict__ b1,
                        const unsigned short* __restrict__ w1c,
                        const float* __restrict__ fscales,
                        unsigned short* __restrict__ h) {
  __shared__ unsigned short xs[BM * D_IN];   // 32 rows x 256 bf16 = 16 KB
  const int t = threadIdx.x;
  const int lane = t & 63;
  const int wv = t >> 6;
  const int l15 = lane & 15;
  const int g = lane >> 4;
  const long row0 = (long)blockIdx.x * BM;
  const float s1 = fscales[0];
  const f32x4 zero4 = {0.f, 0.f, 0.f, 0.f};

  // per-lane weight base: row = 64wv + 16mf + l15, k-offset g*8 (+32/kk)
  const unsigned short* wp = w1c + (64 * wv + l15) * 256 + g * 8;

  // ---- issue weight frags for kk=0,1 FIRST (latency hides under x-stage)
  bf16x8 aw[2][4];
#pragma unroll
  for (int mf = 0; mf < 4; ++mf) {
    aw[0][mf] = *(const bf16x8*)(wp + mf * 4096);
    aw[1][mf] = *(const bf16x8*)(wp + mf * 4096 + 32);
  }

  // ---- stage x tile: thread t covers row r = t>>4, f32 cols (t&15)*16..+16
  {
    const float4* p = (const float4*)x + (long)blockIdx.x * 2048 + (t >> 4) * 64 + (t & 15) * 4;
    float4 v0 = p[0], v1 = p[1], v2 = p[2], v3 = p[3];
    int r = t >> 4, cq = t & 15;
    bf16x8 e0 = cvt8(v0, v1);
    bf16x8 e1 = cvt8(v2, v3);
    int sw = (r & 7) << 2;
    *(bf16x8*)&xs[r * 256 + ((cq * 2) ^ sw) * 8] = e0;
    *(bf16x8*)&xs[r * 256 + ((cq * 2 + 1) ^ sw) * 8] = e1;
  }
  __syncthreads();

  f32x4 acc[4][2];
#pragma unroll
  for (int a = 0; a < 4; ++a) { acc[a][0] = zero4; acc[a][1] = zero4; }

#pragma unroll
  for (int kk = 0; kk < 8; ++kk) {
    bf16x8 a0 = aw[kk & 1][0], a1 = aw[kk & 1][1];
    bf16x8 a2 = aw[kk & 1][2], a3 = aw[kk & 1][3];
    if (kk + 2 < 8) {
#pragma unroll
      for (int mf = 0; mf < 4; ++mf)
        aw[kk & 1][mf] = *(const bf16x8*)(wp + mf * 4096 + (kk + 2) * 32);
    }
    bf16x8 bx[2];
#pragma unroll
    for (int nf = 0; nf < 2; ++nf) {
      int m = 16 * nf + l15;
      int s = (kk * 4 + g) ^ ((m & 7) << 2);
      bx[nf] = *(const bf16x8*)&xs[m * 256 + s * 8];
    }
    acc[0][0] = __builtin_amdgcn_mfma_f32_16x16x32_bf16(a0, bx[0], acc[0][0], 0, 0, 0);
    acc[0][1] = __builtin_amdgcn_mfma_f32_16x16x32_bf16(a0, bx[1], acc[0][1], 0, 0, 0);
    acc[1][0] = __builtin_amdgcn_mfma_f32_16x16x32_bf16(a1, bx[0], acc[1][0], 0, 0, 0);
    acc[1][1] = __builtin_amdgcn_mfma_f32_16x16x32_bf16(a1, bx[1], acc[1][1], 0, 0, 0);
    acc[2][0] = __builtin_amdgcn_mfma_f32_16x16x32_bf16(a2, bx[0], acc[2][0], 0, 0, 0);
    acc[2][1] = __builtin_amdgcn_mfma_f32_16x16x32_bf16(a2, bx[1], acc[2][1], 0, 0, 0);
    acc[3][0] = __builtin_amdgcn_mfma_f32_16x16x32_bf16(a3, bx[0], acc[3][0], 0, 0, 0);
    acc[3][1] = __builtin_amdgcn_mfma_f32_16x16x32_bf16(a3, bx[1], acc[3][1], 0, 0, 0);
  }

  // epilogue: h[m][c] = relu(s1*acc + b1[c]), 8B stores (4 consecutive hidden)
#pragma unroll
  for (int mf = 0; mf < 4; ++mf) {
    int cb = 64 * wv + 16 * mf + 4 * g;
    float4 bb = *(const float4*)&b1[cb];
#pragma unroll
    for (int nf = 0; nf < 2; ++nf) {
      int m = 16 * nf + l15;
      f32x4 a = acc[mf][nf];
      us4 o;
      o.x = f2bf(fmaxf(s1 * a[0] + bb.x, 0.f));
      o.y = f2bf(fmaxf(s1 * a[1] + bb.y, 0.f));
      o.z = f2bf(fmaxf(s1 * a[2] + bb.z, 0.f));
      o.w = f2bf(fmaxf(s1 * a[3] + bb.w, 0.f));
      *(us4*)&h[(row0 + m) * D_HID + cb] = o;
    }
  }
}

// ---------------- K2: out = s2 * (W2q @ h^T) + b2, f32, IN-PLACE over h -----
// 8192 blocks x 512 threads. Block = 32 batch rows. Wave wv owns out cols
// [32wv, 32wv+32). h tile DMA-staged to LDS (32 KB, source-side swizzle);
// all h-reads happen in the stage, so the post-stage barrier orders them
// before any out store (in-place safe; blocks own disjoint rows).
// Weight frags: depth-2 rotating-buffer prefetch from L2-resident w2c.
__launch_bounds__(512)
__global__ void k2_gemm(const unsigned short* __restrict__ h,
                        const float* __restrict__ b2,
                        const unsigned short* __restrict__ w2c,
                        const float* __restrict__ fscales,
                        float* __restrict__ out) {
  __shared__ unsigned short hs[BM * D_HID];  // 32 rows x 512 bf16 = 32 KB
  const int t = threadIdx.x;
  const int lane = t & 63;
  const int wv = t >> 6;
  const int l15 = lane & 15;
  const int g = lane >> 4;
  const long row0 = (long)blockIdx.x * BM;
  const float s2 = fscales[1];
  const f32x4 zero4 = {0.f, 0.f, 0.f, 0.f};

  const unsigned short* wp2 = w2c + (32 * wv + l15) * 512 + g * 8;

  // ---- issue weight frags for kk=0,1 FIRST (fly alongside the DMA)
  bf16x8 aw[2][2];
#pragma unroll
  for (int mf = 0; mf < 2; ++mf) {
    aw[0][mf] = *(const bf16x8*)(wp2 + mf * 8192);
    aw[1][mf] = *(const bf16x8*)(wp2 + mf * 8192 + 32);
  }

  // ---- DMA stage h tile: wave wv stages rows 4wv..4wv+3; LDS slot l holds
  // global chunk l ^ ((m&7)<<2)  (so swizzled read finds linear chunk)
#pragma unroll
  for (int j = 0; j < 4; ++j) {
    int m = wv * 4 + j;
    gload_lds16(&h[(row0 + m) * D_HID + ((lane ^ ((m & 7) << 2)) & 63) * 8],
                &hs[m * D_HID]);
  }
  asm volatile("s_waitcnt vmcnt(0)" ::: "memory");
  __syncthreads();

  f32x4 acc[2][2];
#pragma unroll
  for (int a = 0; a < 2; ++a) { acc[a][0] = zero4; acc[a][1] = zero4; }

#pragma unroll
  for (int kk = 0; kk < 16; ++kk) {
    bf16x8 a0 = aw[kk & 1][0], a1 = aw[kk & 1][1];
    if (kk + 2 < 16) {
      aw[kk & 1][0] = *(const bf16x8*)(wp2 + (kk + 2) * 32);
      aw[kk & 1][1] = *(const bf16x8*)(wp2 + 8192 + (kk + 2) * 32);
    }
    bf16x8 bh[2];
#pragma unroll
    for (int nf = 0; nf < 2; ++nf) {
      int m = 16 * nf + l15;
      int s = (kk * 4 + g) ^ ((m & 7) << 2);
      bh[nf] = *(const bf16x8*)&hs[m * D_HID + s * 8];
    }
    acc[0][0] = __builtin_amdgcn_mfma_f32_16x16x32_bf16(a0, bh[0], acc[0][0], 0, 0, 0);
    acc[0][1] = __builtin_amdgcn_mfma_f32_16x16x32_bf16(a0, bh[1], acc[0][1], 0, 0, 0);
    acc[1][0] = __builtin_amdgcn_mfma_f32_16x16x32_bf16(a1, bh[0], acc[1][0], 0, 0, 0);
    acc[1][1] = __builtin_amdgcn_mfma_f32_16x16x32_bf16(a1, bh[1], acc[1][1], 0, 0, 0);
  }

#pragma unroll
  for (int mf = 0; mf < 2; ++mf) {
    int n4 = 32 * wv + 16 * mf + 4 * g;
    float4 bb = *(const float4*)&b2[n4];
#pragma unroll
    for (int nf = 0; nf < 2; ++nf) {
      int m = 16 * nf + l15;
      f32x4 a = acc[mf][nf];
      float4 o;
      o.x = s2 * a[0] + bb.x;
      o.y = s2 * a[1] + bb.y;
      o.z = s2 * a[2] + bb.z;
      o.w = s2 * a[3] + bb.w;
      *(float4*)&out[(row0 + m) * D_OUT + n4] = o;
    }
  }
}

extern "C" void kernel_launch(void* const* d_in, const int* in_sizes, int n_in,
                              void* d_out, int out_size, void* d_ws, size_t ws_size,
                              hipStream_t stream) {
  const float* x  = (const float*)d_in[0];
  const float* W1 = (const float*)d_in[1];
  const float* b1 = (const float*)d_in[2];
  const float* W2 = (const float*)d_in[3];
  const float* b2 = (const float*)d_in[4];
  float* out = (float*)d_out;

  // ws: [0,128) f64 partials, [128,136) f32 scales, w1c/w2c bf16 at 1024
  double* part = (double*)d_ws;
  float* fsc = (float*)((char*)d_ws + 128);
  unsigned short* w1c = (unsigned short*)((char*)d_ws + 1024);
  unsigned short* w2c = (unsigned short*)((char*)d_ws + 1024 + D_HID * D_IN * 2);

  // h (262144 x 512 bf16 = 268 MB) lives in d_out (262144 x 256 f32 = 268 MB)
  unsigned short* hbuf = (unsigned short*)d_out;

  int Brows = in_sizes[0] / D_IN;     // 262144
  int nblk = Brows / BM;              // 8192

  partial_abs_kernel<<<dim3(16), dim3(1024), 0, stream>>>(W1, W2, part);
  quant_kernel<<<dim3(256), dim3(256), 0, stream>>>(W1, W2, part, w1c, w2c, fsc);
  k1_gemm<<<dim3(nblk), dim3(512), 0, stream>>>(x, b1, w1c, fsc, hbuf);
  k2_gemm<<<dim3(nblk), dim3(512), 0, stream>>>(hbuf, b2, w2c, fsc, out);
}

// Round 14
// 220.097 us; speedup vs baseline: 2.8801x; 2.8801x over previous
//
#include <hip/hip_runtime.h>
#include <hip/hip_bf16.h>

// Problem: out = lecac_linear(relu(lecac_linear(x, W1, b1)), W2, b2)
//   x: [262144, 256] f32, W1: [512,256], b1: [512], W2: [256,512], b2: [256]
// R14: FUSED single-tile blocks with the R10-proven per-wave shape.
// Findings R9-R13: inner-loop global weight loads always land ~320-355us
// (latency exposed, prefetch attempts failed); R10 (codes in 16 regs + unpack)
// = 172+100us, limited by unpack VALU + the h HBM round-trip (83us + k2).
// Fix: one block = one 32-row tile, 8 waves, 48KB LDS (xs 16K + hs 32K),
// stage->L1->epi1(h to LDS, R10-k2 swizzle layout)->L2->store. 2 blocks/CU,
// 8192 blocks stagger phases. Regs ~110 < 128 (first fused fit). Weights as
// packed 2-bit codes (32 u32/thread), v_perm LUT unpack (verified R7-R13).

typedef __attribute__((ext_vector_type(8))) short bf16x8;
typedef __attribute__((ext_vector_type(4))) float f32x4;
typedef __attribute__((ext_vector_type(4))) unsigned short us4;

#define D_IN 256
#define D_HID 512
#define D_OUT 256
#define BM 32

__device__ __forceinline__ unsigned short f2bf(float f) {
  union { __hip_bfloat16 h; unsigned short u; } c;
  c.h = __float2bfloat16(f);
  return c.u;
}

__device__ __forceinline__ bf16x8 cvt8(float4 lo, float4 hi) {
  bf16x8 v;
  v[0] = (short)f2bf(lo.x); v[1] = (short)f2bf(lo.y);
  v[2] = (short)f2bf(lo.z); v[3] = (short)f2bf(lo.w);
  v[4] = (short)f2bf(hi.x); v[5] = (short)f2bf(hi.y);
  v[6] = (short)f2bf(hi.z); v[7] = (short)f2bf(hi.w);
  return v;
}

// Unpack 8 codes (half of a 16-code u32, selected by kkl) -> bf16x8.
// Code c (2 bits): 0->0.0, 1->1.0, 2->-2.0, 3->-1.0. (verified R7-R13)
__device__ __forceinline__ bf16x8 unpack8(unsigned w, int kkl) {
  unsigned te = (w >> (4 * kkl)) & 0x03030303u;        // els j = 0,2,4,6
  unsigned to = (w >> (4 * kkl + 2)) & 0x03030303u;    // els j = 1,3,5,7
  int4 o;
  unsigned s;
  s = __builtin_amdgcn_perm(to, te, 0x04040000u) + 0x00040004u;
  o.x = (int)__builtin_amdgcn_perm(0x80008000u, 0xBFC03F00u, s);
  s = __builtin_amdgcn_perm(to, te, 0x05050101u) + 0x00040004u;
  o.y = (int)__builtin_amdgcn_perm(0x80008000u, 0xBFC03F00u, s);
  s = __builtin_amdgcn_perm(to, te, 0x06060202u) + 0x00040004u;
  o.z = (int)__builtin_amdgcn_perm(0x80008000u, 0xBFC03F00u, s);
  s = __builtin_amdgcn_perm(to, te, 0x07070303u) + 0x00040004u;
  o.w = (int)__builtin_amdgcn_perm(0x80008000u, 0xBFC03F00u, s);
  return *(bf16x8*)&o;
}

// ---- prep 1: deterministic f64 partial abs-sums (8 chunks per tensor) ------
__global__ void partial_abs_kernel(const float* __restrict__ W1,
                                   const float* __restrict__ W2,
                                   double* __restrict__ part) {
  const int b = blockIdx.x;                 // 0..15
  const float* W = (b < 8) ? W1 : W2;
  const float* p = W + (b & 7) * 16384;     // 131072 / 8
  double s = 0.0;
  for (int i = threadIdx.x; i < 16384; i += 1024) s += (double)fabsf(p[i]);
  __shared__ double red[1024];
  red[threadIdx.x] = s;
  __syncthreads();
  for (int st = 512; st > 0; st >>= 1) {
    if (threadIdx.x < st) red[threadIdx.x] += red[threadIdx.x + st];
    __syncthreads();
  }
  if (threadIdx.x == 0) part[b] = red[0];
}

// ---- prep 2: pack 2-bit codes in the per-lane fragment order (R9 layout) ---
// Region 1 (W1, words 0..8191):  word = tt*16 + mf*4 + kp  (mf<4, kp<4)
//   frag row = 64*wv + 16*mf + l15,  k = (2*kp+kkl)*32 + 8*g + j
// Region 2 (W2, words 8192..16383): word = 8192 + tt*16 + mf*8 + kp (mf<2,kp<8)
//   frag row = 32*wv + 16*mf + l15,  k = (2*kp+kkl)*32 + 8*g + j
// Crumb (byte b, crumb c): j = 2b + (c&1), kkl = c>>1.
__global__ void pack_kernel(const float* __restrict__ W1,
                            const float* __restrict__ W2,
                            const double* __restrict__ part,
                            unsigned* __restrict__ pk,
                            float* __restrict__ fscales) {
  int idx = blockIdx.x * 1024 + threadIdx.x;  // 0..16383
  const double* q = part;
  double sA = 1.47 * ((((q[0]+q[1])+(q[2]+q[3]))+((q[4]+q[5])+(q[6]+q[7]))) / 131072.0) + 1e-8;
  double sB = 1.47 * ((((q[8]+q[9])+(q[10]+q[11]))+((q[12]+q[13])+(q[14]+q[15]))) / 131072.0) + 1e-8;
  if (idx == 0) { fscales[0] = (float)sA; fscales[1] = (float)sB; }
  bool is2 = idx >= 8192;
  int r = idx & 8191;
  int tt = r >> 4;                // owner thread 0..511
  int w = r & 15;
  int wv = tt >> 6, lane = tt & 63;
  int l15 = lane & 15, g = (lane >> 4) & 3;
  unsigned word = 0;
  for (int c = 0; c < 4; ++c) {
    for (int b = 0; b < 4; ++b) {
      int j = 2 * b + (c & 1), kkl = c >> 1;
      int code;
      if (!is2) {
        int mf = w >> 2, kp = w & 3;
        int row = 64 * wv + 16 * mf + l15;
        int k = (2 * kp + kkl) * 32 + 8 * g + j;
        double v = rint((double)W1[row * 256 + k] / sA);
        code = (int)fmin(fmax(v, -2.0), 1.0) & 3;
      } else {
        int mf = w >> 3, kp = w & 7;
        int row = 32 * wv + 16 * mf + l15;
        int k = (2 * kp + kkl) * 32 + 8 * g + j;
        double v = rint((double)W2[row * 512 + k] / sB);
        code = (int)fmin(fmax(v, -2.0), 1.0) & 3;
      }
      word |= (unsigned)code << (8 * b + 2 * c);
    }
  }
  pk[idx] = word;
}

// ---------------- fused MLP kernel ------------------------------------------
// 8192 blocks x 512 threads (8 waves); block = one 32-batch-row tile.
// L1: wave wv owns hidden rows [64wv,64wv+64) (mf<4, nf<2, acc1 32 AGPR).
// L2: wave wv owns out cols  [32wv,32wv+32) (mf<2, nf<2, acc2 16 AGPR).
// LDS: xs 16KB + hs 32KB = 48KB -> 2 blocks/CU; phases stagger across blocks.
// hs layout == R10-k2's: 16B slot s of row m holds linear chunk s^((m&7)<<2).
__launch_bounds__(512)
__global__ void fused_mlp(const float* __restrict__ x,
                          const float* __restrict__ b1,
                          const float* __restrict__ b2,
                          const unsigned* __restrict__ pk,
                          const float* __restrict__ fscales,
                          float* __restrict__ out) {
  __shared__ unsigned short xs[BM * D_IN];   // 32 x 256 bf16 = 16 KB
  __shared__ unsigned short hs[BM * D_HID];  // 32 x 512 bf16 = 32 KB
  const int t = threadIdx.x;
  const int lane = t & 63;
  const int wv = t >> 6;
  const int l15 = lane & 15;
  const int g = lane >> 4;
  const long row0 = (long)blockIdx.x * BM;
  const float s1 = fscales[0];
  const float s2 = fscales[1];
  const f32x4 zero4 = {0.f, 0.f, 0.f, 0.f};

  // ---- packed weight codes: 32 u32/thread, loaded once (pk is L2-resident)
  unsigned w1k[16], w2k[16];
  {
    const uint4* p1 = (const uint4*)pk + t * 4;
    const uint4* p2 = (const uint4*)pk + 2048 + t * 4;   // +8192 words
#pragma unroll
    for (int i = 0; i < 4; ++i) {
      uint4 a = p1[i], b = p2[i];
      w1k[4*i] = a.x; w1k[4*i+1] = a.y; w1k[4*i+2] = a.z; w1k[4*i+3] = a.w;
      w2k[4*i] = b.x; w2k[4*i+1] = b.y; w2k[4*i+2] = b.z; w2k[4*i+3] = b.w;
    }
  }

  // ---- stage x tile: thread t covers row r = t>>4, f32 cols (t&15)*16..+16
  {
    const float4* p = (const float4*)x + (long)blockIdx.x * 2048 + (t >> 4) * 64 + (t & 15) * 4;
    float4 v0 = p[0], v1 = p[1], v2 = p[2], v3 = p[3];
    int r = t >> 4, cq = t & 15;
    bf16x8 e0 = cvt8(v0, v1);
    bf16x8 e1 = cvt8(v2, v3);
    int sw = (r & 7) << 2;
    *(bf16x8*)&xs[r * 256 + ((cq * 2) ^ sw) * 8] = e0;
    *(bf16x8*)&xs[r * 256 + ((cq * 2 + 1) ^ sw) * 8] = e1;
  }
  __syncthreads();

  // ========== L1: acc1 = W1q * xs^T (K=256, 8 kk) ==========
  f32x4 acc1[4][2];
#pragma unroll
  for (int a = 0; a < 4; ++a) { acc1[a][0] = zero4; acc1[a][1] = zero4; }
#pragma unroll
  for (int kp = 0; kp < 4; ++kp) {
#pragma unroll
    for (int kkl = 0; kkl < 2; ++kkl) {
      int kk = 2 * kp + kkl;
      bf16x8 bx[2];
#pragma unroll
      for (int nf = 0; nf < 2; ++nf) {
        int m = 16 * nf + l15;
        int s = (kk * 4 + g) ^ ((m & 7) << 2);
        bx[nf] = *(const bf16x8*)&xs[m * 256 + s * 8];
      }
#pragma unroll
      for (int mf = 0; mf < 4; ++mf) {
        bf16x8 fr = unpack8(w1k[mf * 4 + kp], kkl);
        acc1[mf][0] = __builtin_amdgcn_mfma_f32_16x16x32_bf16(fr, bx[0], acc1[mf][0], 0, 0, 0);
        acc1[mf][1] = __builtin_amdgcn_mfma_f32_16x16x32_bf16(fr, bx[1], acc1[mf][1], 0, 0, 0);
      }
    }
  }

  // ========== epi1: hs[m][c] = relu(s1*acc1 + b1[c]), swizzled LDS ==========
  // linear 16B-chunk of cb = 8wv + 2mf + (g>>1); half = g&1 (4 elems);
  // stored at slot chunk^((m&7)<<2)  (matches L2 read pattern below)
#pragma unroll
  for (int mf = 0; mf < 4; ++mf) {
    int cb = 64 * wv + 16 * mf + 4 * g;
    float4 bb = *(const float4*)&b1[cb];
    int chunk = 8 * wv + 2 * mf + (g >> 1);
    int half = (g & 1) * 4;
#pragma unroll
    for (int nf = 0; nf < 2; ++nf) {
      int m = 16 * nf + l15;
      f32x4 a = acc1[mf][nf];
      us4 o;
      o.x = f2bf(fmaxf(s1 * a[0] + bb.x, 0.f));
      o.y = f2bf(fmaxf(s1 * a[1] + bb.y, 0.f));
      o.z = f2bf(fmaxf(s1 * a[2] + bb.z, 0.f));
      o.w = f2bf(fmaxf(s1 * a[3] + bb.w, 0.f));
      int slot = chunk ^ ((m & 7) << 2);
      *(us4*)&hs[m * D_HID + slot * 8 + half] = o;
    }
  }
  __syncthreads();

  // ========== L2: acc2 = W2q * hs^T (K=512, 16 kk) ==========
  f32x4 acc2[2][2];
#pragma unroll
  for (int a = 0; a < 2; ++a) { acc2[a][0] = zero4; acc2[a][1] = zero4; }
#pragma unroll
  for (int kp = 0; kp < 8; ++kp) {
#pragma unroll
    for (int kkl = 0; kkl < 2; ++kkl) {
      int kk = 2 * kp + kkl;
      bf16x8 bh[2];
#pragma unroll
      for (int nf = 0; nf < 2; ++nf) {
        int m = 16 * nf + l15;
        int s = (kk * 4 + g) ^ ((m & 7) << 2);
        bh[nf] = *(const bf16x8*)&hs[m * D_HID + s * 8];
      }
#pragma unroll
      for (int mf = 0; mf < 2; ++mf) {
        bf16x8 fr = unpack8(w2k[mf * 8 + kp], kkl);
        acc2[mf][0] = __builtin_amdgcn_mfma_f32_16x16x32_bf16(fr, bh[0], acc2[mf][0], 0, 0, 0);
        acc2[mf][1] = __builtin_amdgcn_mfma_f32_16x16x32_bf16(fr, bh[1], acc2[mf][1], 0, 0, 0);
      }
    }
  }

  // ========== epi2: out[m][n] = s2*acc2 + b2[n], float4 stores ==========
#pragma unroll
  for (int mf = 0; mf < 2; ++mf) {
    int n4 = 32 * wv + 16 * mf + 4 * g;
    float4 bb = *(const float4*)&b2[n4];
#pragma unroll
    for (int nf = 0; nf < 2; ++nf) {
      int m = 16 * nf + l15;
      f32x4 a = acc2[mf][nf];
      float4 o;
      o.x = s2 * a[0] + bb.x;
      o.y = s2 * a[1] + bb.y;
      o.z = s2 * a[2] + bb.z;
      o.w = s2 * a[3] + bb.w;
      *(float4*)&out[(row0 + m) * D_OUT + n4] = o;
    }
  }
}

extern "C" void kernel_launch(void* const* d_in, const int* in_sizes, int n_in,
                              void* d_out, int out_size, void* d_ws, size_t ws_size,
                              hipStream_t stream) {
  const float* x  = (const float*)d_in[0];
  const float* W1 = (const float*)d_in[1];
  const float* b1 = (const float*)d_in[2];
  const float* W2 = (const float*)d_in[3];
  const float* b2 = (const float*)d_in[4];
  float* out = (float*)d_out;

  // ws layout: [0,128) f64 partials, [128,136) f32 scales, pk at 1024 (64 KB)
  double* part = (double*)d_ws;
  float* fsc = (float*)((char*)d_ws + 128);
  unsigned* pk = (unsigned*)((char*)d_ws + 1024);

  int Brows = in_sizes[0] / D_IN;     // 262144
  int nblk = Brows / BM;              // 8192

  partial_abs_kernel<<<dim3(16), dim3(1024), 0, stream>>>(W1, W2, part);
  pack_kernel<<<dim3(16), dim3(1024), 0, stream>>>(W1, W2, part, pk, fsc);
  fused_mlp<<<dim3(nblk), dim3(512), 0, stream>>>(x, b1, b2, pk, fsc, out);
}